// Round 8
// baseline (277.637 us; speedup 1.0000x reference)
//
#include <hip/hip_runtime.h>
#include <hip/hip_fp16.h>

#define NN 50000
#define NE 800000
#define D 128
#define H 4
#define CH 32
#define NEG 0.2f
#define CAP 64          // bucket slots per node; deg is Poisson(16), P(>64) ~ 1e-13

#define BSH 10                       // bin = dst >> 10 (1024 nodes per bin)
#define NBIN 49                      // ceil(50000 / 1024)
#define BCAP 256                     // LDS slots per bin per block
#define PCAP 24576                   // global pair slots per bin (expected ~16.3k)
#define EPB 8192                     // edges per phase-1 block

__global__ void k_zero(int* __restrict__ gcnt) {
    int i = threadIdx.x;
    if (i < NBIN) gcnt[i] = 0;
}

// ---- Phase 1: bin edges by dst>>10, coalesced flush to per-bin pair regions ----
__global__ __launch_bounds__(256) void k_bin(const int* __restrict__ src,
                                             const int* __restrict__ dst,
                                             int* __restrict__ gcnt,
                                             unsigned int* __restrict__ pairbuf) {
    __shared__ int bcnt[NBIN];
    __shared__ int bbase[NBIN];
    __shared__ unsigned int lbuf[NBIN][BCAP];
    int tid = threadIdx.x;
    int e0 = blockIdx.x * EPB;

    for (int b = tid; b < NBIN; b += 256) bcnt[b] = 0;
    __syncthreads();

    #pragma unroll
    for (int i = 0; i < EPB / 256; i++) {
        int e = e0 + i * 256 + tid;
        if (e < NE) {
            int d = dst[e];
            int s = src[e];
            int bin = d >> BSH;
            unsigned int pack = ((unsigned int)(d & ((1 << BSH) - 1)) << 16) | (unsigned int)s;
            int pos = atomicAdd(&bcnt[bin], 1);
            if (pos < BCAP) {
                lbuf[bin][pos] = pack;
            } else {                       // ~never: direct global fallback
                int gp = atomicAdd(&gcnt[bin], 1);
                if (gp < PCAP) pairbuf[(size_t)bin * PCAP + gp] = pack;
            }
        }
    }
    __syncthreads();
    if (tid < NBIN) {
        int c = bcnt[tid]; if (c > BCAP) c = BCAP;
        bbase[tid] = atomicAdd(&gcnt[tid], c);
    }
    __syncthreads();
    for (int b = 0; b < NBIN; b++) {
        int c = bcnt[b]; if (c > BCAP) c = BCAP;
        int base = bbase[b];
        for (int i = tid; i < c; i += 256)
            pairbuf[(size_t)b * PCAP + base + i] = lbuf[b][i];
    }
}

// ---- Phase 2: one block per bin; LDS deg counters; single-writer bucket lines ----
__global__ __launch_bounds__(256) void k_place(const int* __restrict__ gcnt,
                                               const unsigned int* __restrict__ pairbuf,
                                               int* __restrict__ fill,
                                               int* __restrict__ bucket) {
    __shared__ int ldeg[1 << BSH];
    int tid = threadIdx.x;
    int b = blockIdx.x;
    for (int i = tid; i < (1 << BSH); i += 256) ldeg[i] = 0;
    __syncthreads();

    int cnt = gcnt[b]; if (cnt > PCAP) cnt = PCAP;
    int nbase = b << BSH;
    for (int i = tid; i < cnt; i += 256) {
        unsigned int p = pairbuf[(size_t)b * PCAP + i];
        int nl = p >> 16;
        int s = p & 0xFFFF;
        int pos = atomicAdd(&ldeg[nl], 1);
        if (pos < CAP) bucket[((nbase + nl) << 6) + pos] = s;
    }
    __syncthreads();
    for (int nl = tid; nl < (1 << BSH); nl += 256) {
        int n = nbase + nl;
        if (n < NN) { int d = ldeg[nl]; fill[n] = d > CAP ? CAP : d; }
    }
}

// Register-tiled GEMM (xs = x @ Wsrc, stored fp16) + fused attention-logit matvecs.
// BM=64 (grid 782 -> ~3 blocks/CU), BN=128, BK=32, 256 threads, 4x8 acc per thread.
__global__ __launch_bounds__(256, 4) void k_gemm_al(
        const float* __restrict__ x,
        const float* __restrict__ Ws, const float* __restrict__ Wd,
        const float* __restrict__ attS, const float* __restrict__ attD,
        __half* __restrict__ xs, float* __restrict__ als, float* __restrict__ ald) {
    __shared__ float xsh[32][68];    // x chunk transposed [k][r]
    __shared__ float wsh[32][128];   // Wsrc chunk [kk][c]
    __shared__ float efsh[8][132];   // weff [o][k]; o<4: src heads, o>=4: dst heads
    __shared__ float attsh[8][32];

    int tid = threadIdx.x;
    int n0 = blockIdx.x * 64;

    {
        int o = tid >> 5, c = tid & 31;
        attsh[o][c] = (o < 4) ? attS[o * CH + c] : attD[(o - 4) * CH + c];
    }
    __syncthreads();
    #pragma unroll
    for (int p = 0; p < 4; p++) {
        int idx = p * 256 + tid;       // o*128 + k
        int o = idx >> 7, k = idx & 127;
        const float* Wo = (o < 4) ? Ws : Wd;
        int hh = o & 3;
        float s = 0.f;
        #pragma unroll
        for (int c = 0; c < CH; c += 4) {
            float4 wv = *(const float4*)(Wo + (size_t)k * D + hh * CH + c);
            float4 av = *(const float4*)&attsh[o][c];
            s += wv.x * av.x + wv.y * av.y + wv.z * av.z + wv.w * av.w;
        }
        efsh[o][k] = s;
    }

    int tr = tid >> 4, tc = tid & 15, o = tc & 7;
    float acc[4][8];
    #pragma unroll
    for (int i = 0; i < 4; i++)
        #pragma unroll
        for (int j = 0; j < 8; j++) acc[i][j] = 0.f;
    float alacc[4] = {0.f, 0.f, 0.f, 0.f};

    int c4 = tid & 7, rr = tid >> 3;     // staging map: 8 col-quads x 32 rows

    for (int chnk = 0; chnk < 4; chnk++) {
        __syncthreads();
        // stage x chunk transposed: 64 rows x 32 cols
        #pragma unroll
        for (int j = 0; j < 2; j++) {
            int r = rr + j * 32;
            int rg = n0 + r; if (rg >= NN) rg = NN - 1;
            float4 v = *(const float4*)(x + (size_t)rg * D + chnk * 32 + c4 * 4);
            xsh[c4 * 4 + 0][r] = v.x; xsh[c4 * 4 + 1][r] = v.y;
            xsh[c4 * 4 + 2][r] = v.z; xsh[c4 * 4 + 3][r] = v.w;
        }
        // stage W chunk (rows chnk*32..+31), linear
        #pragma unroll
        for (int j = 0; j < 4; j++) {
            int f = j * 256 + tid;
            float4 v = *(const float4*)(Ws + (size_t)chnk * 32 * D + f * 4);
            *(float4*)&wsh[0][f * 4] = v;
        }
        __syncthreads();
        #pragma unroll
        for (int kk = 0; kk < 32; kk++) {
            float4 xa = *(const float4*)&xsh[kk][tr * 4];
            float4 w0 = *(const float4*)&wsh[kk][tc * 4];
            float4 w1 = *(const float4*)&wsh[kk][64 + tc * 4];
            float ef = efsh[o][chnk * 32 + kk];
            float xr[4] = {xa.x, xa.y, xa.z, xa.w};
            float wc[8] = {w0.x, w0.y, w0.z, w0.w, w1.x, w1.y, w1.z, w1.w};
            #pragma unroll
            for (int i = 0; i < 4; i++) {
                #pragma unroll
                for (int j = 0; j < 8; j++) acc[i][j] = fmaf(xr[i], wc[j], acc[i][j]);
                alacc[i] = fmaf(xr[i], ef, alacc[i]);
            }
        }
    }

    // ---- epilogue: xs stored as fp16 ----
    #pragma unroll
    for (int i = 0; i < 4; i++) {
        int row = n0 + tr * 4 + i;
        if (row < NN) {
            __half2 h0 = __floats2half2_rn(acc[i][0], acc[i][1]);
            __half2 h1 = __floats2half2_rn(acc[i][2], acc[i][3]);
            __half2 h2 = __floats2half2_rn(acc[i][4], acc[i][5]);
            __half2 h3 = __floats2half2_rn(acc[i][6], acc[i][7]);
            __half2* p0 = (__half2*)&xs[(size_t)row * D + tc * 4];
            __half2* p1 = (__half2*)&xs[(size_t)row * D + 64 + tc * 4];
            p0[0] = h0; p0[1] = h1;
            p1[0] = h2; p1[1] = h3;
            if (tc < 8) {
                if (o < 4) als[row * H + o] = alacc[i];
                else       ald[row * H + (o - 4)] = alacc[i];
            }
        }
    }
}

// Fused softmax + aggregate. One wave per node, 4 waves/block.
__global__ __launch_bounds__(256) void k_fused(const int* __restrict__ fill,
                                               const int* __restrict__ bucket,
                                               const float* __restrict__ als,
                                               const float* __restrict__ ald,
                                               const __half* __restrict__ xs,
                                               const float* __restrict__ bias,
                                               float* __restrict__ out,
                                               int do_relu) {
    __shared__ float wlds[4][256];
    __shared__ int   slds[4][64];
    int wv = threadIdx.x >> 6, lane = threadIdx.x & 63;
    int n = blockIdx.x * 4 + wv;
    int deg = fill[n]; if (deg > CAP) deg = CAP;
    int start = n << 6;
    int half = lane >> 5, sl = lane & 31;

    if (deg == 0) {
        if (half == 0) {
            float4 b4 = *(const float4*)&bias[sl * 4];
            if (do_relu) {
                b4.x = fmaxf(b4.x, 0.f); b4.y = fmaxf(b4.y, 0.f);
                b4.z = fmaxf(b4.z, 0.f); b4.w = fmaxf(b4.w, 0.f);
            }
            *(float4*)&out[(size_t)n * D + sl * 4] = b4;
        }
        return;
    }

    int slot = lane >> 2, h = lane & 3;
    float adv = ald[n * H + h];
    int dm1 = deg - 1;

    // ---- pass 1: logits for up to 64 edges (4 per lane, batched) ----
    int i0 = slot, i1 = slot + 16, i2 = slot + 32, i3 = slot + 48;
    int s0 = bucket[start + min(i0, dm1)];
    int s1 = bucket[start + min(i1, dm1)];
    int s2 = bucket[start + min(i2, dm1)];
    int s3 = bucket[start + min(i3, dm1)];
    float a0 = als[s0 * H + h] + adv;
    float a1 = als[s1 * H + h] + adv;
    float a2 = als[s2 * H + h] + adv;
    float a3 = als[s3 * H + h] + adv;
    a0 = a0 > 0.f ? a0 : NEG * a0;
    a1 = a1 > 0.f ? a1 : NEG * a1;
    a2 = a2 > 0.f ? a2 : NEG * a2;
    a3 = a3 > 0.f ? a3 : NEG * a3;
    float lg0 = (i0 < deg) ? a0 : -1e30f;
    float lg1 = (i1 < deg) ? a1 : -1e30f;
    float lg2 = (i2 < deg) ? a2 : -1e30f;
    float lg3 = (i3 < deg) ? a3 : -1e30f;
    float m = fmaxf(fmaxf(lg0, lg1), fmaxf(lg2, lg3));
    #pragma unroll
    for (int msk = 4; msk < 64; msk <<= 1) m = fmaxf(m, __shfl_xor(m, msk, 64));

    float w0 = (i0 < deg) ? __expf(lg0 - m) : 0.f;
    float w1 = (i1 < deg) ? __expf(lg1 - m) : 0.f;
    float w2 = (i2 < deg) ? __expf(lg2 - m) : 0.f;
    float w3 = (i3 < deg) ? __expf(lg3 - m) : 0.f;
    float sm = w0 + w1 + w2 + w3;
    #pragma unroll
    for (int msk = 4; msk < 64; msk <<= 1) sm += __shfl_xor(sm, msk, 64);

    wlds[wv][i0 * 4 + h] = w0;
    wlds[wv][i1 * 4 + h] = w1;
    wlds[wv][i2 * 4 + h] = w2;
    wlds[wv][i3 * 4 + h] = w3;
    if (h == 0) {
        slds[wv][i0] = s0; slds[wv][i1] = s1; slds[wv][i2] = s2; slds[wv][i3] = s3;
    }

    // ---- pass 2: aggregate fp16 rows; half-wave per edge, 8B per lane ----
    float invh = 1.f / (sm + 1e-16f);
    int h2 = sl >> 3;
    float inv4 = __shfl(invh, h2, 64);

    float ax = 0.f, ay = 0.f, az = 0.f, aw = 0.f;
    int capR = (deg + 3) & ~3;
    for (int e = 0; e < capR; e += 4) {
        int iA = e + half, iB = e + 2 + half;
        int tA = slds[wv][iA];
        int tB = slds[wv][iB];
        float wA = wlds[wv][iA * 4 + h2];
        float wB = wlds[wv][iB * 4 + h2];
        uint2 uA = *(const uint2*)&xs[(size_t)tA * D + sl * 4];
        uint2 uB = *(const uint2*)&xs[(size_t)tB * D + sl * 4];
        float2 fA0 = __half22float2(__builtin_bit_cast(__half2, uA.x));
        float2 fA1 = __half22float2(__builtin_bit_cast(__half2, uA.y));
        float2 fB0 = __half22float2(__builtin_bit_cast(__half2, uB.x));
        float2 fB1 = __half22float2(__builtin_bit_cast(__half2, uB.y));
        ax = fmaf(wA, fA0.x, ax); ay = fmaf(wA, fA0.y, ay);
        az = fmaf(wA, fA1.x, az); aw = fmaf(wA, fA1.y, aw);
        ax = fmaf(wB, fB0.x, ax); ay = fmaf(wB, fB0.y, ay);
        az = fmaf(wB, fB1.x, az); aw = fmaf(wB, fB1.y, aw);
    }

    ax += __shfl_xor(ax, 32, 64);
    ay += __shfl_xor(ay, 32, 64);
    az += __shfl_xor(az, 32, 64);
    aw += __shfl_xor(aw, 32, 64);

    if (half == 0) {
        float4 b4 = *(const float4*)&bias[sl * 4];
        float4 o4;
        o4.x = ax * inv4 + b4.x;
        o4.y = ay * inv4 + b4.y;
        o4.z = az * inv4 + b4.z;
        o4.w = aw * inv4 + b4.w;
        if (do_relu) {
            o4.x = fmaxf(o4.x, 0.f); o4.y = fmaxf(o4.y, 0.f);
            o4.z = fmaxf(o4.z, 0.f); o4.w = fmaxf(o4.w, 0.f);
        }
        *(float4*)&out[(size_t)n * D + sl * 4] = o4;
    }
}

extern "C" void kernel_launch(void* const* d_in, const int* in_sizes, int n_in,
                              void* d_out, int out_size, void* d_ws, size_t ws_size,
                              hipStream_t stream) {
    const float* x_in   = (const float*)d_in[0];
    const int*   edge   = (const int*)d_in[1];
    const float* Wsrc   = (const float*)d_in[2];
    const float* Wdst   = (const float*)d_in[3];
    const float* attsrc = (const float*)d_in[4];
    const float* attdst = (const float*)d_in[5];
    const float* bias   = (const float*)d_in[6];
    float* out = (float*)d_out;

    const int* src = edge;
    const int* dst = edge + NE;

    char* ws = (char*)d_ws;
    size_t off = 0;
    auto alloc = [&](size_t bytes) -> void* {
        void* p = ws + off;
        off += (bytes + 255) & ~(size_t)255;
        return p;
    };

    int* fill    = (int*)alloc(NN * sizeof(int));
    int* bucket  = (int*)alloc((size_t)NN * CAP * sizeof(int));
    int* gcnt    = (int*)alloc(NBIN * sizeof(int));
    unsigned int* pairbuf = (unsigned int*)alloc((size_t)NBIN * PCAP * sizeof(int));
    __half* xs   = (__half*)alloc((size_t)NN * D * sizeof(__half));
    float* als   = (float*)alloc(NN * H * sizeof(float));
    float* ald   = (float*)alloc(NN * H * sizeof(float));
    float* bufA  = (float*)alloc((size_t)NN * D * sizeof(float));
    float* bufB  = (float*)alloc((size_t)NN * D * sizeof(float));

    // ---- bucketed CSR build: zero counters, bin by dst range, place ----
    k_zero<<<1, 64, 0, stream>>>(gcnt);
    k_bin<<<(NE + EPB - 1) / EPB, 256, 0, stream>>>(src, dst, gcnt, pairbuf);
    k_place<<<NBIN, 256, 0, stream>>>(gcnt, pairbuf, fill, bucket);

    // ---- 3 GAT layers ----
    for (int l = 0; l < 3; l++) {
        const float* xin  = (l == 0) ? x_in : ((l == 1) ? bufA : bufB);
        float*       xout = (l == 2) ? out : ((l == 0) ? bufA : bufB);
        const float* Ws = Wsrc + (size_t)l * D * D;
        const float* Wd = Wdst + (size_t)l * D * D;

        k_gemm_al<<<(NN + 63) / 64, 256, 0, stream>>>(
            xin, Ws, Wd, attsrc + l * H * CH, attdst + l * H * CH, xs, als, ald);
        k_fused<<<NN / 4, 256, 0, stream>>>(fill, bucket, als, ald, xs,
                                            bias + l * D, xout, (l < 2) ? 1 : 0);
    }
}

// Round 9
// 263.439 us; speedup vs baseline: 1.0539x; 1.0539x over previous
//
#include <hip/hip_runtime.h>
#include <hip/hip_fp16.h>

#define NN 50000
#define NE 800000
#define D 128
#define H 4
#define CH 32
#define NEG 0.2f
#define CAP 64          // bucket slots per node; deg is Poisson(16), P(>64) ~ 1e-13

#define BSH 10                       // bin = dst >> 10 (1024 nodes per bin)
#define NBIN 49                      // ceil(50000 / 1024)
#define BCAP 256                     // LDS slots per bin per block
#define PCAP 24576                   // global pair slots per bin (expected ~16.3k)
#define EPB 8192                     // edges per phase-1 block

__global__ void k_zero(int* __restrict__ gcnt) {
    int i = threadIdx.x;
    if (i < NBIN) gcnt[i] = 0;
}

// ---- Phase 1: bin edges by dst>>10, coalesced flush to per-bin pair regions ----
__global__ __launch_bounds__(256) void k_bin(const int* __restrict__ src,
                                             const int* __restrict__ dst,
                                             int* __restrict__ gcnt,
                                             unsigned int* __restrict__ pairbuf) {
    __shared__ int bcnt[NBIN];
    __shared__ int bbase[NBIN];
    __shared__ unsigned int lbuf[NBIN][BCAP];
    int tid = threadIdx.x;
    int e0 = blockIdx.x * EPB;

    for (int b = tid; b < NBIN; b += 256) bcnt[b] = 0;
    __syncthreads();

    #pragma unroll
    for (int i = 0; i < EPB / 256; i++) {
        int e = e0 + i * 256 + tid;
        if (e < NE) {
            int d = dst[e];
            int s = src[e];
            int bin = d >> BSH;
            unsigned int pack = ((unsigned int)(d & ((1 << BSH) - 1)) << 16) | (unsigned int)s;
            int pos = atomicAdd(&bcnt[bin], 1);
            if (pos < BCAP) {
                lbuf[bin][pos] = pack;
            } else {                       // ~never: direct global fallback
                int gp = atomicAdd(&gcnt[bin], 1);
                if (gp < PCAP) pairbuf[(size_t)bin * PCAP + gp] = pack;
            }
        }
    }
    __syncthreads();
    if (tid < NBIN) {
        int c = bcnt[tid]; if (c > BCAP) c = BCAP;
        bbase[tid] = atomicAdd(&gcnt[tid], c);
    }
    __syncthreads();
    for (int b = 0; b < NBIN; b++) {
        int c = bcnt[b]; if (c > BCAP) c = BCAP;
        int base = bbase[b];
        for (int i = tid; i < c; i += 256)
            pairbuf[(size_t)b * PCAP + base + i] = lbuf[b][i];
    }
}

// ---- Phase 2: one block per bin; LDS deg counters; single-writer bucket lines ----
__global__ __launch_bounds__(256) void k_place(const int* __restrict__ gcnt,
                                               const unsigned int* __restrict__ pairbuf,
                                               int* __restrict__ fill,
                                               int* __restrict__ bucket) {
    __shared__ int ldeg[1 << BSH];
    int tid = threadIdx.x;
    int b = blockIdx.x;
    for (int i = tid; i < (1 << BSH); i += 256) ldeg[i] = 0;
    __syncthreads();

    int cnt = gcnt[b]; if (cnt > PCAP) cnt = PCAP;
    int nbase = b << BSH;
    for (int i = tid; i < cnt; i += 256) {
        unsigned int p = pairbuf[(size_t)b * PCAP + i];
        int nl = p >> 16;
        int s = p & 0xFFFF;
        int pos = atomicAdd(&ldeg[nl], 1);
        if (pos < CAP) bucket[((nbase + nl) << 6) + pos] = s;
    }
    __syncthreads();
    for (int nl = tid; nl < (1 << BSH); nl += 256) {
        int n = nbase + nl;
        if (n < NN) { int d = ldeg[nl]; fill[n] = d > CAP ? CAP : d; }
    }
}

// ---- weff for ALL layers, one dispatch: weff[l][o][k] = sum_c W(l,o)[k][hh*32+c]*att(l,o)[c]
// blockIdx = l*8+o (24 blocks), 128 threads (one k each).
__global__ void k_weff(const float* __restrict__ Wsrc, const float* __restrict__ Wdst,
                       const float* __restrict__ attS, const float* __restrict__ attD,
                       float* __restrict__ weff) {
    int bo = blockIdx.x;
    int l = bo >> 3, o = bo & 7, hh = o & 3;
    int k = threadIdx.x;
    const float* W = ((o < 4) ? Wsrc : Wdst) + (size_t)l * D * D;
    const float* att = ((o < 4) ? attS : attD) + l * H * CH + hh * CH;
    float s = 0.f;
    #pragma unroll
    for (int c = 0; c < CH; c += 4) {
        float4 wv = *(const float4*)(W + (size_t)k * D + hh * CH + c);
        s += wv.x * att[c] + wv.y * att[c + 1] + wv.z * att[c + 2] + wv.w * att[c + 3];
    }
    weff[bo * 128 + k] = s;
}

// Register-tiled GEMM (xs = x @ Wsrc, stored fp16) + fused attention-logit matvecs.
// BM=64, BN=128, BK=32, 256 threads, 4x8 acc. Software-pipelined: chunk t+1's
// global loads issue before chunk t's compute, hiding HBM/L2 latency.
__global__ __launch_bounds__(256, 3) void k_gemm_al(
        const float* __restrict__ x, const float* __restrict__ Ws,
        const float* __restrict__ weff,
        __half* __restrict__ xs, float* __restrict__ als, float* __restrict__ ald) {
    __shared__ float xsh[32][68];    // x chunk transposed [k][r]
    __shared__ float wsh[32][128];   // W chunk [kk][c] (linear 4096 floats)
    __shared__ float efsh[8][132];   // weff [o][k]

    int tid = threadIdx.x;
    int n0 = blockIdx.x * 64;

    // efsh: 1024 floats, 1 float4/thread
    {
        int idx = tid * 4;
        int o = idx >> 7, k = idx & 127;
        float4 v = *(const float4*)&weff[idx];
        *(float4*)&efsh[o][k] = v;
    }

    int c4 = tid & 7, rr = tid >> 3;     // x staging map: 8 col-quads x 32 rows
    int rg0 = n0 + rr;      if (rg0 >= NN) rg0 = NN - 1;
    int rg1 = n0 + rr + 32; if (rg1 >= NN) rg1 = NN - 1;
    const float* xp0 = x + (size_t)rg0 * D + c4 * 4;
    const float* xp1 = x + (size_t)rg1 * D + c4 * 4;

    // prefetch chunk 0
    float4 px0 = *(const float4*)(xp0);
    float4 px1 = *(const float4*)(xp1);
    float4 pw0 = *(const float4*)(Ws + (size_t)(0 * 256 + tid) * 4);
    float4 pw1 = *(const float4*)(Ws + (size_t)(1 * 256 + tid) * 4);
    float4 pw2 = *(const float4*)(Ws + (size_t)(2 * 256 + tid) * 4);
    float4 pw3 = *(const float4*)(Ws + (size_t)(3 * 256 + tid) * 4);

    int tr = tid >> 4, tc = tid & 15, o = tc & 7;
    float acc[4][8];
    #pragma unroll
    for (int i = 0; i < 4; i++)
        #pragma unroll
        for (int j = 0; j < 8; j++) acc[i][j] = 0.f;
    float alacc[4] = {0.f, 0.f, 0.f, 0.f};

    for (int chnk = 0; chnk < 4; chnk++) {
        __syncthreads();   // prior compute done (iter 0: no-op ordering for efsh)
        // write prefetched chunk (compiler inserts vmcnt wait)
        xsh[c4 * 4 + 0][rr] = px0.x; xsh[c4 * 4 + 1][rr] = px0.y;
        xsh[c4 * 4 + 2][rr] = px0.z; xsh[c4 * 4 + 3][rr] = px0.w;
        xsh[c4 * 4 + 0][rr + 32] = px1.x; xsh[c4 * 4 + 1][rr + 32] = px1.y;
        xsh[c4 * 4 + 2][rr + 32] = px1.z; xsh[c4 * 4 + 3][rr + 32] = px1.w;
        *(float4*)&wsh[0][(0 * 256 + tid) * 4] = pw0;
        *(float4*)&wsh[0][(1 * 256 + tid) * 4] = pw1;
        *(float4*)&wsh[0][(2 * 256 + tid) * 4] = pw2;
        *(float4*)&wsh[0][(3 * 256 + tid) * 4] = pw3;
        __syncthreads();   // staged data visible
        if (chnk < 3) {    // issue next chunk's loads; compute hides their latency
            int nc = chnk + 1;
            px0 = *(const float4*)(xp0 + nc * 32);
            px1 = *(const float4*)(xp1 + nc * 32);
            const float* Wp = Ws + (size_t)nc * 32 * D;
            pw0 = *(const float4*)(Wp + (size_t)(0 * 256 + tid) * 4);
            pw1 = *(const float4*)(Wp + (size_t)(1 * 256 + tid) * 4);
            pw2 = *(const float4*)(Wp + (size_t)(2 * 256 + tid) * 4);
            pw3 = *(const float4*)(Wp + (size_t)(3 * 256 + tid) * 4);
        }
        #pragma unroll
        for (int kk = 0; kk < 32; kk++) {
            float4 xa = *(const float4*)&xsh[kk][tr * 4];
            float4 w0 = *(const float4*)&wsh[kk][tc * 4];
            float4 w1 = *(const float4*)&wsh[kk][64 + tc * 4];
            float ef = efsh[o][chnk * 32 + kk];
            float xr[4] = {xa.x, xa.y, xa.z, xa.w};
            float wc[8] = {w0.x, w0.y, w0.z, w0.w, w1.x, w1.y, w1.z, w1.w};
            #pragma unroll
            for (int i = 0; i < 4; i++) {
                #pragma unroll
                for (int j = 0; j < 8; j++) acc[i][j] = fmaf(xr[i], wc[j], acc[i][j]);
                alacc[i] = fmaf(xr[i], ef, alacc[i]);
            }
        }
    }

    // ---- epilogue: xs stored as fp16 ----
    #pragma unroll
    for (int i = 0; i < 4; i++) {
        int row = n0 + tr * 4 + i;
        if (row < NN) {
            __half2 h0 = __floats2half2_rn(acc[i][0], acc[i][1]);
            __half2 h1 = __floats2half2_rn(acc[i][2], acc[i][3]);
            __half2 h2 = __floats2half2_rn(acc[i][4], acc[i][5]);
            __half2 h3 = __floats2half2_rn(acc[i][6], acc[i][7]);
            __half2* p0 = (__half2*)&xs[(size_t)row * D + tc * 4];
            __half2* p1 = (__half2*)&xs[(size_t)row * D + 64 + tc * 4];
            p0[0] = h0; p0[1] = h1;
            p1[0] = h2; p1[1] = h3;
            if (tc < 8) {
                if (o < 4) als[row * H + o] = alacc[i];
                else       ald[row * H + (o - 4)] = alacc[i];
            }
        }
    }
}

// Fused softmax + aggregate. One wave per node, 4 waves/block.
__global__ __launch_bounds__(256) void k_fused(const int* __restrict__ fill,
                                               const int* __restrict__ bucket,
                                               const float* __restrict__ als,
                                               const float* __restrict__ ald,
                                               const __half* __restrict__ xs,
                                               const float* __restrict__ bias,
                                               float* __restrict__ out,
                                               int do_relu) {
    __shared__ float wlds[4][256];
    __shared__ int   slds[4][64];
    int wv = threadIdx.x >> 6, lane = threadIdx.x & 63;
    int n = blockIdx.x * 4 + wv;
    int deg = fill[n]; if (deg > CAP) deg = CAP;
    int start = n << 6;
    int half = lane >> 5, sl = lane & 31;

    if (deg == 0) {
        if (half == 0) {
            float4 b4 = *(const float4*)&bias[sl * 4];
            if (do_relu) {
                b4.x = fmaxf(b4.x, 0.f); b4.y = fmaxf(b4.y, 0.f);
                b4.z = fmaxf(b4.z, 0.f); b4.w = fmaxf(b4.w, 0.f);
            }
            *(float4*)&out[(size_t)n * D + sl * 4] = b4;
        }
        return;
    }

    int slot = lane >> 2, h = lane & 3;
    float adv = ald[n * H + h];
    int dm1 = deg - 1;

    // ---- pass 1: logits for up to 64 edges (4 per lane, batched) ----
    int i0 = slot, i1 = slot + 16, i2 = slot + 32, i3 = slot + 48;
    int s0 = bucket[start + min(i0, dm1)];
    int s1 = bucket[start + min(i1, dm1)];
    int s2 = bucket[start + min(i2, dm1)];
    int s3 = bucket[start + min(i3, dm1)];
    float a0 = als[s0 * H + h] + adv;
    float a1 = als[s1 * H + h] + adv;
    float a2 = als[s2 * H + h] + adv;
    float a3 = als[s3 * H + h] + adv;
    a0 = a0 > 0.f ? a0 : NEG * a0;
    a1 = a1 > 0.f ? a1 : NEG * a1;
    a2 = a2 > 0.f ? a2 : NEG * a2;
    a3 = a3 > 0.f ? a3 : NEG * a3;
    float lg0 = (i0 < deg) ? a0 : -1e30f;
    float lg1 = (i1 < deg) ? a1 : -1e30f;
    float lg2 = (i2 < deg) ? a2 : -1e30f;
    float lg3 = (i3 < deg) ? a3 : -1e30f;
    float m = fmaxf(fmaxf(lg0, lg1), fmaxf(lg2, lg3));
    #pragma unroll
    for (int msk = 4; msk < 64; msk <<= 1) m = fmaxf(m, __shfl_xor(m, msk, 64));

    float w0 = (i0 < deg) ? __expf(lg0 - m) : 0.f;
    float w1 = (i1 < deg) ? __expf(lg1 - m) : 0.f;
    float w2 = (i2 < deg) ? __expf(lg2 - m) : 0.f;
    float w3 = (i3 < deg) ? __expf(lg3 - m) : 0.f;
    float sm = w0 + w1 + w2 + w3;
    #pragma unroll
    for (int msk = 4; msk < 64; msk <<= 1) sm += __shfl_xor(sm, msk, 64);

    wlds[wv][i0 * 4 + h] = w0;
    wlds[wv][i1 * 4 + h] = w1;
    wlds[wv][i2 * 4 + h] = w2;
    wlds[wv][i3 * 4 + h] = w3;
    if (h == 0) {
        slds[wv][i0] = s0; slds[wv][i1] = s1; slds[wv][i2] = s2; slds[wv][i3] = s3;
    }

    // ---- pass 2: aggregate fp16 rows; half-wave per edge, 8B per lane ----
    float invh = 1.f / (sm + 1e-16f);
    int h2 = sl >> 3;
    float inv4 = __shfl(invh, h2, 64);

    float ax = 0.f, ay = 0.f, az = 0.f, aw = 0.f;
    int capR = (deg + 3) & ~3;
    for (int e = 0; e < capR; e += 4) {
        int iA = e + half, iB = e + 2 + half;
        int tA = slds[wv][iA];
        int tB = slds[wv][iB];
        float wA = wlds[wv][iA * 4 + h2];
        float wB = wlds[wv][iB * 4 + h2];
        uint2 uA = *(const uint2*)&xs[(size_t)tA * D + sl * 4];
        uint2 uB = *(const uint2*)&xs[(size_t)tB * D + sl * 4];
        float2 fA0 = __half22float2(__builtin_bit_cast(__half2, uA.x));
        float2 fA1 = __half22float2(__builtin_bit_cast(__half2, uA.y));
        float2 fB0 = __half22float2(__builtin_bit_cast(__half2, uB.x));
        float2 fB1 = __half22float2(__builtin_bit_cast(__half2, uB.y));
        ax = fmaf(wA, fA0.x, ax); ay = fmaf(wA, fA0.y, ay);
        az = fmaf(wA, fA1.x, az); aw = fmaf(wA, fA1.y, aw);
        ax = fmaf(wB, fB0.x, ax); ay = fmaf(wB, fB0.y, ay);
        az = fmaf(wB, fB1.x, az); aw = fmaf(wB, fB1.y, aw);
    }

    ax += __shfl_xor(ax, 32, 64);
    ay += __shfl_xor(ay, 32, 64);
    az += __shfl_xor(az, 32, 64);
    aw += __shfl_xor(aw, 32, 64);

    if (half == 0) {
        float4 b4 = *(const float4*)&bias[sl * 4];
        float4 o4;
        o4.x = ax * inv4 + b4.x;
        o4.y = ay * inv4 + b4.y;
        o4.z = az * inv4 + b4.z;
        o4.w = aw * inv4 + b4.w;
        if (do_relu) {
            o4.x = fmaxf(o4.x, 0.f); o4.y = fmaxf(o4.y, 0.f);
            o4.z = fmaxf(o4.z, 0.f); o4.w = fmaxf(o4.w, 0.f);
        }
        *(float4*)&out[(size_t)n * D + sl * 4] = o4;
    }
}

extern "C" void kernel_launch(void* const* d_in, const int* in_sizes, int n_in,
                              void* d_out, int out_size, void* d_ws, size_t ws_size,
                              hipStream_t stream) {
    const float* x_in   = (const float*)d_in[0];
    const int*   edge   = (const int*)d_in[1];
    const float* Wsrc   = (const float*)d_in[2];
    const float* Wdst   = (const float*)d_in[3];
    const float* attsrc = (const float*)d_in[4];
    const float* attdst = (const float*)d_in[5];
    const float* bias   = (const float*)d_in[6];
    float* out = (float*)d_out;

    const int* src = edge;
    const int* dst = edge + NE;

    char* ws = (char*)d_ws;
    size_t off = 0;
    auto alloc = [&](size_t bytes) -> void* {
        void* p = ws + off;
        off += (bytes + 255) & ~(size_t)255;
        return p;
    };

    int* fill    = (int*)alloc(NN * sizeof(int));
    int* bucket  = (int*)alloc((size_t)NN * CAP * sizeof(int));
    int* gcnt    = (int*)alloc(NBIN * sizeof(int));
    unsigned int* pairbuf = (unsigned int*)alloc((size_t)NBIN * PCAP * sizeof(int));
    __half* xs   = (__half*)alloc((size_t)NN * D * sizeof(__half));
    float* als   = (float*)alloc(NN * H * sizeof(float));
    float* ald   = (float*)alloc(NN * H * sizeof(float));
    float* weff  = (float*)alloc(3 * 8 * 128 * sizeof(float));
    float* bufA  = (float*)alloc((size_t)NN * D * sizeof(float));
    float* bufB  = (float*)alloc((size_t)NN * D * sizeof(float));

    // ---- CSR build + weff precompute (independent; weff for all 3 layers) ----
    k_zero<<<1, 64, 0, stream>>>(gcnt);
    k_weff<<<24, 128, 0, stream>>>(Wsrc, Wdst, attsrc, attdst, weff);
    k_bin<<<(NE + EPB - 1) / EPB, 256, 0, stream>>>(src, dst, gcnt, pairbuf);
    k_place<<<NBIN, 256, 0, stream>>>(gcnt, pairbuf, fill, bucket);

    // ---- 3 GAT layers ----
    for (int l = 0; l < 3; l++) {
        const float* xin  = (l == 0) ? x_in : ((l == 1) ? bufA : bufB);
        float*       xout = (l == 2) ? out : ((l == 0) ? bufA : bufB);
        const float* Ws = Wsrc + (size_t)l * D * D;

        k_gemm_al<<<(NN + 63) / 64, 256, 0, stream>>>(
            xin, Ws, weff + l * 8 * 128, xs, als, ald);
        k_fused<<<NN / 4, 256, 0, stream>>>(fill, bucket, als, ald, xs,
                                            bias + l * D, xout, (l < 2) ? 1 : 0);
    }
}